// Round 4
// baseline (219.661 us; speedup 1.0000x reference)
//
#include <hip/hip_runtime.h>
#include <hip/hip_bf16.h>

// N=8192, D=128, NUM_CLASSES=1000
#define CN 8192
#define CD 128
#define NCLS 1000

typedef __attribute__((ext_vector_type(8))) short bf16x8;
typedef __attribute__((ext_vector_type(4))) float f32x4;

// ---- ws layout (bytes) ----
// [0x000000) Abf : 2 MB bf16
// [0x200000) Bbf : 2 MB bf16
// [0x400000) hist: 1000 int (pad 4 KB)
// [0x401000) rowE: 32 KB
// [0x409000) colE: 32 KB
// [0x411000) g   : 1000x128 f32 (512 KB slot)
// [0x491000) h   : 1000x128 f32 (512 KB slot)
#define WS_B_OFF    0x200000u
#define WS_HIST_OFF 0x400000u
#define WS_ROWE_OFF 0x401000u
#define WS_COLE_OFF 0x409000u
#define WS_G_OFF    0x411000u
#define WS_H_OFF    0x491000u
#define WS_ZERO_BYTES 0x111000u   // hist + rowE + colE + g + h

__device__ inline unsigned short f2bf(float f) {
    unsigned int u = __float_as_uint(f);
    unsigned int r = (u + 0x7FFFu + ((u >> 16) & 1u)) >> 16;   // RNE
    return (unsigned short)r;
}

__global__ void convert_kernel(const float* __restrict__ fa, const float* __restrict__ fb,
                               unsigned short* __restrict__ Abf, unsigned short* __restrict__ Bbf) {
    const float* src = blockIdx.y == 0 ? fa : fb;
    unsigned short* dst = blockIdx.y == 0 ? Abf : Bbf;
    int i = (blockIdx.x * 256 + threadIdx.x) * 4;
    float4 v = *reinterpret_cast<const float4*>(src + i);
    ushort4 o;
    o.x = f2bf(v.x); o.y = f2bf(v.y); o.z = f2bf(v.z); o.w = f2bf(v.w);
    *reinterpret_cast<ushort4*>(dst + i) = o;
}

__global__ void hist_kernel(const int* __restrict__ targets, int* __restrict__ hist) {
    int i = blockIdx.x * blockDim.x + threadIdx.x;
    if (i < CN) atomicAdd(&hist[targets[i]], 1);
}

// g[c] = sum of fb rows with target c ; h[c] = sum of fa rows with target c  (f32 exact)
__global__ void classsum_kernel(const float* __restrict__ fa, const float* __restrict__ fb,
                                const int* __restrict__ tgt,
                                float* __restrict__ g, float* __restrict__ h) {
    int gid = blockIdx.x * 256 + threadIdx.x;   // CN*32 threads
    int j = gid >> 5, d = (gid & 31) * 4;
    int t = tgt[j];
    float4 va = *reinterpret_cast<const float4*>(fa + (size_t)j * CD + d);
    float4 vb = *reinterpret_cast<const float4*>(fb + (size_t)j * CD + d);
    float* hp = h + (size_t)t * CD + d;
    float* gp = g + (size_t)t * CD + d;
    atomicAdd(hp + 0, va.x); atomicAdd(hp + 1, va.y);
    atomicAdd(hp + 2, va.z); atomicAdd(hp + 3, va.w);
    atomicAdd(gp + 0, vb.x); atomicAdd(gp + 1, vb.y);
    atomicAdd(gp + 2, vb.z); atomicAdd(gp + 3, vb.w);
}

// One 128(row)x64(col) tile of S = T*(fa.fb^T); accumulate exp(s-T) row & col sums.
// LDS 48 KB -> 3 blocks/CU. Staging: global_load_lds w=16, linear LDS dest +
// inverse-XOR-swizzled global source; reads apply the same involution (rule 21).
__global__ __launch_bounds__(256) void tile_kernel(
    const float* __restrict__ Tptr,
    const unsigned short* __restrict__ Abf,
    const unsigned short* __restrict__ Bbf,
    float* __restrict__ rowE_g, float* __restrict__ colE_g)
{
    __shared__ __align__(16) unsigned short sA[128 * 128];
    __shared__ __align__(16) unsigned short sB[64 * 128];

    const int tid  = threadIdx.x;
    const int brow = blockIdx.y * 128;
    const int bcol = blockIdx.x * 64;
    const float T   = Tptr[0];
    const float Tl2 = T * 1.44269504088896340736f;   // T*log2(e)

    #pragma unroll
    for (int it = 0; it < 8; ++it) {               // A: 2048 x 16B chunks
        int idx = it * 256 + tid;
        int r = idx >> 4, q = idx & 15;
        const unsigned short* src = Abf + (size_t)(brow + r) * CD + ((q ^ (r & 7)) * 8);
        __builtin_amdgcn_global_load_lds((const __attribute__((address_space(1))) void*)src,
                                         (__attribute__((address_space(3))) void*)&sA[idx * 8],
                                         16, 0, 0);
    }
    #pragma unroll
    for (int it = 0; it < 4; ++it) {               // B: 1024 x 16B chunks
        int idx = it * 256 + tid;
        int r = idx >> 4, q = idx & 15;
        const unsigned short* src = Bbf + (size_t)(bcol + r) * CD + ((q ^ (r & 7)) * 8);
        __builtin_amdgcn_global_load_lds((const __attribute__((address_space(1))) void*)src,
                                         (__attribute__((address_space(3))) void*)&sB[idx * 8],
                                         16, 0, 0);
    }
    __syncthreads();

    const int lane = tid & 63;
    const int w    = tid >> 6;          // wave owns rows w*32 .. w*32+31, all 64 cols
    const int colg = lane & 15;
    const int rowg = lane >> 4;

    f32x4 acc[2][4];
    #pragma unroll
    for (int m = 0; m < 2; ++m)
        #pragma unroll
        for (int n = 0; n < 4; ++n)
            acc[m][n] = (f32x4){0.f, 0.f, 0.f, 0.f};

    #pragma unroll
    for (int kk = 0; kk < 4; ++kk) {
        bf16x8 af[2], bfr[4];
        #pragma unroll
        for (int m = 0; m < 2; ++m) {
            int r = w * 32 + m * 16 + colg;
            int slot = (kk * 4 + rowg) ^ (r & 7);
            af[m] = *reinterpret_cast<const bf16x8*>(&sA[r * 128 + slot * 8]);
        }
        #pragma unroll
        for (int n = 0; n < 4; ++n) {
            int r = n * 16 + colg;
            int slot = (kk * 4 + rowg) ^ (r & 7);
            bfr[n] = *reinterpret_cast<const bf16x8*>(&sB[r * 128 + slot * 8]);
        }
        #pragma unroll
        for (int m = 0; m < 2; ++m)
            #pragma unroll
            for (int n = 0; n < 4; ++n)
                acc[m][n] = __builtin_amdgcn_mfma_f32_16x16x32_bf16(af[m], bfr[n], acc[m][n], 0, 0, 0);
    }

    // epilogue: e = exp2(Tl2*(d-1)) ; D layout: col = lane&15, row = rowg*4+j (m89)
    float rE[2][4] = {{0.f}};
    float cE[4] = {0.f, 0.f, 0.f, 0.f};
    #pragma unroll
    for (int m = 0; m < 2; ++m)
        #pragma unroll
        for (int n = 0; n < 4; ++n)
            #pragma unroll
            for (int j = 0; j < 4; ++j) {
                float e = exp2f(__builtin_fmaf(acc[m][n][j], Tl2, -Tl2));
                rE[m][j] += e;
                cE[n]    += e;
            }

    // row sums: fold 16 col-groups (lane bits 0..3)
    #pragma unroll
    for (int m = 0; m < 2; ++m)
        #pragma unroll
        for (int j = 0; j < 4; ++j) {
            float e = rE[m][j];
            #pragma unroll
            for (int off = 1; off < 16; off <<= 1) e += __shfl_xor(e, off);
            if (colg == 0)
                atomicAdd(&rowE_g[brow + w * 32 + m * 16 + rowg * 4 + j], e);
        }
    // col sums: fold 4 row-groups (lane bits 4..5)
    #pragma unroll
    for (int n = 0; n < 4; ++n) {
        float e = cE[n];
        e += __shfl_xor(e, 16);
        e += __shfl_xor(e, 32);
        if (rowg == 0)
            atomicAdd(&colE_g[bcol + n * 16 + colg], e);
    }
}

__global__ __launch_bounds__(256) void lse_kernel(
    const float* __restrict__ Tptr,
    const float* __restrict__ rowE, const float* __restrict__ colE,
    float* __restrict__ out)
{
    __shared__ float red[4];
    const int tid = threadIdx.x;
    int i = blockIdx.x * 256 + tid;              // 0..16383
    const float T = Tptr[0];
    float se = i < CN ? rowE[i] : colE[i - CN];
    float v = T + logf(se);
    #pragma unroll
    for (int off = 1; off < 64; off <<= 1) v += __shfl_xor(v, off);
    if ((tid & 63) == 0) red[tid >> 6] = v;
    __syncthreads();
    if (tid == 0) {
        float tot = red[0] + red[1] + red[2] + red[3];
        atomicAdd(out, tot * (1.0f / (2.0f * (float)CN)));
    }
}

// out += -(T/N) * sum_c (g[c].h[c]) / hist[c]
__global__ __launch_bounds__(256) void classdot_kernel(
    const float* __restrict__ Tptr, const int* __restrict__ hist,
    const float* __restrict__ g, const float* __restrict__ h,
    float* __restrict__ out)
{
    __shared__ float red[4];
    const int tid = threadIdx.x;
    int c = blockIdx.x * 256 + tid;
    float s = 0.f;
    if (c < NCLS) {
        int cnt = hist[c];
        if (cnt > 0) {
            float acc = 0.f;
            #pragma unroll 4
            for (int d = 0; d < CD; d += 4) {
                float4 vg = *reinterpret_cast<const float4*>(g + (size_t)c * CD + d);
                float4 vh = *reinterpret_cast<const float4*>(h + (size_t)c * CD + d);
                acc += vg.x * vh.x + vg.y * vh.y + vg.z * vh.z + vg.w * vh.w;
            }
            s = acc / (float)cnt;
        }
    }
    #pragma unroll
    for (int off = 1; off < 64; off <<= 1) s += __shfl_xor(s, off);
    if ((tid & 63) == 0) red[tid >> 6] = s;
    __syncthreads();
    if (tid == 0) {
        float tot = red[0] + red[1] + red[2] + red[3];
        atomicAdd(out, -(Tptr[0] / (float)CN) * tot);
    }
}

extern "C" void kernel_launch(void* const* d_in, const int* in_sizes, int n_in,
                              void* d_out, int out_size, void* d_ws, size_t ws_size,
                              hipStream_t stream) {
    const float* T  = (const float*)d_in[0];
    const float* fa = (const float*)d_in[1];
    const float* fb = (const float*)d_in[2];
    const int* tgt  = (const int*)d_in[3];
    float* out      = (float*)d_out;

    char* ws = (char*)d_ws;
    unsigned short* Abf = (unsigned short*)ws;
    unsigned short* Bbf = (unsigned short*)(ws + WS_B_OFF);
    int*   hist = (int*)(ws + WS_HIST_OFF);
    float* rowE = (float*)(ws + WS_ROWE_OFF);
    float* colE = (float*)(ws + WS_COLE_OFF);
    float* g    = (float*)(ws + WS_G_OFF);
    float* h    = (float*)(ws + WS_H_OFF);

    hipMemsetAsync(out, 0, sizeof(float), stream);
    hipMemsetAsync(ws + WS_HIST_OFF, 0, WS_ZERO_BYTES, stream);

    convert_kernel<<<dim3(CN * CD / (256 * 4), 2), 256, 0, stream>>>(fa, fb, Abf, Bbf);
    hist_kernel<<<CN / 256, 256, 0, stream>>>(tgt, hist);
    classsum_kernel<<<CN * 32 / 256, 256, 0, stream>>>(fa, fb, tgt, g, h);

    dim3 grid(CN / 64, CN / 128);
    tile_kernel<<<grid, 256, 0, stream>>>(T, Abf, Bbf, rowE, colE);

    lse_kernel<<<2 * CN / 256, 256, 0, stream>>>(T, rowE, colE, out);
    classdot_kernel<<<(NCLS + 255) / 256, 256, 0, stream>>>(T, hist, g, h, out);
}

// Round 8
// 144.262 us; speedup vs baseline: 1.5227x; 1.5227x over previous
//
#include <hip/hip_runtime.h>
#include <hip/hip_bf16.h>

// N=8192, D=128, NUM_CLASSES=1000
#define CN 8192
#define CD 128
#define NCLS 1000
#define MAXC 256   // max rows per class (random targets: observed max ~25; guard clamps)

typedef __attribute__((ext_vector_type(8))) short bf16x8;
typedef __attribute__((ext_vector_type(4))) float f32x4;

// ---- ws layout (bytes) ----
// 0x000000 Abf 2MB | 0x200000 Bbf 2MB
// 0x400000 cnt 4KB | 0x401000 extra 4KB
// 0x402000 rowE 32KB | 0x40A000 colE 32KB          (fallback atomic mode)
// 0x412000 bucket ushort 1000*256*2 = 500KB
// 0x490000 rowPart 128*8192*4 = 4MB                (store mode)
// 0x890000 colPart  64*8192*4 = 2MB  -> end 0xA90000
#define WS_B_OFF     0x200000u
#define WS_CNT_OFF   0x400000u
#define WS_EXTRA_OFF 0x401000u
#define WS_ROWE_OFF  0x402000u
#define WS_COLE_OFF  0x40A000u
#define WS_BKT_OFF   0x412000u
#define WS_ROWP_OFF  0x490000u
#define WS_COLP_OFF  0x890000u
#define WS_FAST_BYTES 0xA90000u
#define WS_ZERO_BYTES 0x12000u   // cnt + extra + rowE + colE

__device__ inline unsigned short f2bf(float f) {
    unsigned int u = __float_as_uint(f);
    return (unsigned short)((u + 0x7FFFu + ((u >> 16) & 1u)) >> 16);   // RNE
}

// f32 -> bf16 for both matrices; fused per-row class-bucket build (blockIdx.y==0).
__global__ void convert_kernel(const float* __restrict__ fa, const float* __restrict__ fb,
                               unsigned short* __restrict__ Abf, unsigned short* __restrict__ Bbf,
                               const int* __restrict__ tgt,
                               int* __restrict__ cnt, unsigned short* __restrict__ bucket) {
    int gid = blockIdx.x * 256 + threadIdx.x;
    int i = gid * 4;
    const float* src = blockIdx.y == 0 ? fa : fb;
    unsigned short* dst = blockIdx.y == 0 ? Abf : Bbf;
    float4 v = *reinterpret_cast<const float4*>(src + i);
    ushort4 o;
    o.x = f2bf(v.x); o.y = f2bf(v.y); o.z = f2bf(v.z); o.w = f2bf(v.w);
    *reinterpret_cast<ushort4*>(dst + i) = o;

    if (blockIdx.y == 0 && (gid & 31) == 0) {
        int row = gid >> 5;                 // i / CD
        int t = tgt[row];
        int slot = atomicAdd(&cnt[t], 1);
        if (slot < MAXC) bucket[t * MAXC + slot] = (unsigned short)row;
    }
}

// One wave per class: exact f32 class sums h[c]=sum fa rows, g[c]=sum fb rows,
// then extra[c] = -2*T*(h.g)/n_c   (0 if empty class).
__global__ __launch_bounds__(64) void classsum_kernel(
    const float* __restrict__ Tptr,
    const float* __restrict__ fa, const float* __restrict__ fb,
    const int* __restrict__ cnt, const unsigned short* __restrict__ bucket,
    float* __restrict__ extra) {
    const int c = blockIdx.x;
    const int lane = threadIdx.x;
    const int n = cnt[c];
    const int m = n < MAXC ? n : MAXC;
    const float* src = lane < 32 ? fa : fb;
    const int d = (lane & 31) * 4;
    float ax = 0.f, ay = 0.f, az = 0.f, aw = 0.f;
    for (int s = 0; s < m; ++s) {
        int row = bucket[c * MAXC + s];
        float4 v = *reinterpret_cast<const float4*>(src + (size_t)row * CD + d);
        ax += v.x; ay += v.y; az += v.z; aw += v.w;
    }
    // pair lanes l <-> l+32: product h_d*g_d per dim slice
    float bx_ = __shfl_xor(ax, 32), by_ = __shfl_xor(ay, 32);
    float bz_ = __shfl_xor(az, 32), bw_ = __shfl_xor(aw, 32);
    float p = ax * bx_ + ay * by_ + az * bz_ + aw * bw_;
    // fold each 32-lane half (halves hold identical products)
    #pragma unroll
    for (int off = 1; off < 32; off <<= 1) p += __shfl_xor(p, off);
    if (lane == 0) extra[c] = n > 0 ? (-2.0f * Tptr[0] * p / (float)n) : 0.f;
}

// One 128(row)x64(col) tile of S = T*(fa.fb^T); row/col sums of exp(s-T).
// store_mode=1: plain stores to per-tile partial arrays (no atomics).
// Col partials are reduced across the 4 waves in LDS first -> ONE writer per
// column per block (round-6 bug: 4 waves plain-stored the same slot).
__global__ __launch_bounds__(256) void tile_kernel(
    const float* __restrict__ Tptr,
    const unsigned short* __restrict__ Abf,
    const unsigned short* __restrict__ Bbf,
    float* __restrict__ rowE, float* __restrict__ colE,
    float* __restrict__ rowPart, float* __restrict__ colPart,
    int store_mode)
{
    __shared__ __align__(16) unsigned short sA[128 * 128];
    __shared__ __align__(16) unsigned short sB[64 * 128];
    __shared__ float colRed[4][64];

    const int tid  = threadIdx.x;
    const int brow = blockIdx.y * 128;
    const int bcol = blockIdx.x * 64;
    const float T   = Tptr[0];
    const float Tl2 = T * 1.44269504088896340736f;   // T*log2(e)

    #pragma unroll
    for (int it = 0; it < 8; ++it) {               // A: 2048 x 16B chunks
        int idx = it * 256 + tid;
        int r = idx >> 4, q = idx & 15;
        const unsigned short* src = Abf + (size_t)(brow + r) * CD + ((q ^ (r & 7)) * 8);
        __builtin_amdgcn_global_load_lds((const __attribute__((address_space(1))) void*)src,
                                         (__attribute__((address_space(3))) void*)&sA[idx * 8],
                                         16, 0, 0);
    }
    #pragma unroll
    for (int it = 0; it < 4; ++it) {               // B: 1024 x 16B chunks
        int idx = it * 256 + tid;
        int r = idx >> 4, q = idx & 15;
        const unsigned short* src = Bbf + (size_t)(bcol + r) * CD + ((q ^ (r & 7)) * 8);
        __builtin_amdgcn_global_load_lds((const __attribute__((address_space(1))) void*)src,
                                         (__attribute__((address_space(3))) void*)&sB[idx * 8],
                                         16, 0, 0);
    }
    __syncthreads();

    const int lane = tid & 63;
    const int w    = tid >> 6;          // wave owns rows w*32..w*32+31, all 64 cols
    const int colg = lane & 15;
    const int rowg = lane >> 4;

    f32x4 acc[2][4];
    #pragma unroll
    for (int m = 0; m < 2; ++m)
        #pragma unroll
        for (int n = 0; n < 4; ++n)
            acc[m][n] = (f32x4){0.f, 0.f, 0.f, 0.f};

    #pragma unroll
    for (int kk = 0; kk < 4; ++kk) {
        bf16x8 af[2], bfr[4];
        #pragma unroll
        for (int m = 0; m < 2; ++m) {
            int r = w * 32 + m * 16 + colg;
            int slot = (kk * 4 + rowg) ^ (r & 7);
            af[m] = *reinterpret_cast<const bf16x8*>(&sA[r * 128 + slot * 8]);
        }
        #pragma unroll
        for (int n = 0; n < 4; ++n) {
            int r = n * 16 + colg;
            int slot = (kk * 4 + rowg) ^ (r & 7);
            bfr[n] = *reinterpret_cast<const bf16x8*>(&sB[r * 128 + slot * 8]);
        }
        #pragma unroll
        for (int m = 0; m < 2; ++m)
            #pragma unroll
            for (int n = 0; n < 4; ++n)
                acc[m][n] = __builtin_amdgcn_mfma_f32_16x16x32_bf16(af[m], bfr[n], acc[m][n], 0, 0, 0);
    }

    // epilogue: e = exp2(Tl2*(d-1)); D layout: col = lane&15, row = rowg*4+j (m89)
    float rE[2][4] = {{0.f}};
    float cE[4] = {0.f, 0.f, 0.f, 0.f};
    #pragma unroll
    for (int m = 0; m < 2; ++m)
        #pragma unroll
        for (int n = 0; n < 4; ++n)
            #pragma unroll
            for (int j = 0; j < 4; ++j) {
                float e = exp2f(__builtin_fmaf(acc[m][n][j], Tl2, -Tl2));
                rE[m][j] += e;
                cE[n]    += e;
            }

    // row sums: fold 16 col-groups (lane bits 0..3); one writer per row slot
    #pragma unroll
    for (int m = 0; m < 2; ++m)
        #pragma unroll
        for (int j = 0; j < 4; ++j) {
            float e = rE[m][j];
            #pragma unroll
            for (int off = 1; off < 16; off <<= 1) e += __shfl_xor(e, off);
            if (colg == 0) {
                int row = brow + w * 32 + m * 16 + rowg * 4 + j;
                if (store_mode) rowPart[(size_t)blockIdx.x * CN + row] = e;
                else            atomicAdd(&rowE[row], e);
            }
        }
    // col sums: fold 4 row-groups (lane bits 4..5), per-wave partial -> LDS
    #pragma unroll
    for (int n = 0; n < 4; ++n) {
        float e = cE[n];
        e += __shfl_xor(e, 16);
        e += __shfl_xor(e, 32);
        if (rowg == 0) colRed[w][n * 16 + colg] = e;
    }
    __syncthreads();
    // cross-wave reduce: ONE writer per column per block
    if (tid < 64) {
        float s = colRed[0][tid] + colRed[1][tid] + colRed[2][tid] + colRed[3][tid];
        if (store_mode) colPart[(size_t)blockIdx.y * CN + bcol + tid] = s;
        else            atomicAdd(&colE[bcol + tid], s);
    }
}

// Sum partials, add lse terms and class terms, scale 1/(2N).
__global__ __launch_bounds__(256) void finalize_kernel(
    const float* __restrict__ Tptr,
    const float* __restrict__ rowE, const float* __restrict__ colE,
    const float* __restrict__ rowPart, const float* __restrict__ colPart,
    const float* __restrict__ extra,
    float* __restrict__ out, int store_mode)
{
    __shared__ float red[4];
    const int tid = threadIdx.x;
    int i = blockIdx.x * 256 + tid;              // 0 .. 2*CN+NCLS-1 (padded)
    const float T = Tptr[0];
    float v = 0.f;
    if (i < CN) {
        float se;
        if (store_mode) {
            se = 0.f;
            #pragma unroll 4
            for (int p = 0; p < 128; ++p) se += rowPart[(size_t)p * CN + i];
        } else se = rowE[i];
        v = T + logf(se);
    } else if (i < 2 * CN) {
        int c = i - CN;
        float se;
        if (store_mode) {
            se = 0.f;
            #pragma unroll 4
            for (int p = 0; p < 64; ++p) se += colPart[(size_t)p * CN + c];
        } else se = colE[c];
        v = T + logf(se);
    } else if (i < 2 * CN + NCLS) {
        v = extra[i - 2 * CN];
    }
    #pragma unroll
    for (int off = 1; off < 64; off <<= 1) v += __shfl_xor(v, off);
    if ((tid & 63) == 0) red[tid >> 6] = v;
    __syncthreads();
    if (tid == 0) {
        float tot = red[0] + red[1] + red[2] + red[3];
        atomicAdd(out, tot * (1.0f / (2.0f * (float)CN)));
    }
}

extern "C" void kernel_launch(void* const* d_in, const int* in_sizes, int n_in,
                              void* d_out, int out_size, void* d_ws, size_t ws_size,
                              hipStream_t stream) {
    const float* T  = (const float*)d_in[0];
    const float* fa = (const float*)d_in[1];
    const float* fb = (const float*)d_in[2];
    const int* tgt  = (const int*)d_in[3];
    float* out      = (float*)d_out;

    char* ws = (char*)d_ws;
    unsigned short* Abf = (unsigned short*)ws;
    unsigned short* Bbf = (unsigned short*)(ws + WS_B_OFF);
    int*   cnt    = (int*)(ws + WS_CNT_OFF);
    float* extra  = (float*)(ws + WS_EXTRA_OFF);
    float* rowE   = (float*)(ws + WS_ROWE_OFF);
    float* colE   = (float*)(ws + WS_COLE_OFF);
    unsigned short* bucket = (unsigned short*)(ws + WS_BKT_OFF);
    float* rowPart = (float*)(ws + WS_ROWP_OFF);
    float* colPart = (float*)(ws + WS_COLP_OFF);

    const int store_mode = (ws_size >= WS_FAST_BYTES) ? 1 : 0;

    hipMemsetAsync(out, 0, sizeof(float), stream);
    hipMemsetAsync(ws + WS_CNT_OFF, 0, WS_ZERO_BYTES, stream);

    convert_kernel<<<dim3(CN * CD / (256 * 4), 2), 256, 0, stream>>>(fa, fb, Abf, Bbf, tgt, cnt, bucket);
    classsum_kernel<<<NCLS, 64, 0, stream>>>(T, fa, fb, cnt, bucket, extra);

    dim3 grid(CN / 64, CN / 128);
    tile_kernel<<<grid, 256, 0, stream>>>(T, Abf, Bbf, rowE, colE, rowPart, colPart, store_mode);

    finalize_kernel<<<(2 * CN + NCLS + 255) / 256, 256, 0, stream>>>(
        T, rowE, colE, rowPart, colPart, extra, out, store_mode);
}

// Round 10
// 131.367 us; speedup vs baseline: 1.6721x; 1.0982x over previous
//
#include <hip/hip_runtime.h>
#include <hip/hip_bf16.h>

// N=8192, D=128, NUM_CLASSES=1000
#define CN 8192
#define CD 128
#define NCLS 1000
#define MAXC 256

typedef __attribute__((ext_vector_type(8))) short bf16x8;
typedef __attribute__((ext_vector_type(4))) float f32x4;

// ---- ws layout (bytes) ----
// 0x000000 Abf 2MB | 0x200000 Bbf 2MB
// 0x400000 cnt 4KB | 0x401000 extra 4KB
// 0x402000 rowE 32KB | 0x40A000 colE 32KB      (fallback atomic mode)
// 0x412000 bucket ushort 1000*256*2 = 500KB
// 0x490000 rowPart 8*8192*4 = 256KB            (store mode)
// 0x890000 colPart 64*8192*4 = 2MB -> end 0xA90000
#define WS_B_OFF     0x200000u
#define WS_CNT_OFF   0x400000u
#define WS_EXTRA_OFF 0x401000u
#define WS_ROWE_OFF  0x402000u
#define WS_COLE_OFF  0x40A000u
#define WS_BKT_OFF   0x412000u
#define WS_ROWP_OFF  0x490000u
#define WS_COLP_OFF  0x890000u
#define WS_FAST_BYTES 0xA90000u
#define WS_ZERO_BYTES 0x12000u   // cnt + extra + rowE + colE

__device__ inline unsigned short f2bf(float f) {
    unsigned int u = __float_as_uint(f);
    return (unsigned short)((u + 0x7FFFu + ((u >> 16) & 1u)) >> 16);   // RNE
}

// f32 -> bf16 for both matrices; fused per-row class-bucket build (blockIdx.y==0).
__global__ void convert_kernel(const float* __restrict__ fa, const float* __restrict__ fb,
                               unsigned short* __restrict__ Abf, unsigned short* __restrict__ Bbf,
                               const int* __restrict__ tgt,
                               int* __restrict__ cnt, unsigned short* __restrict__ bucket) {
    int gid = blockIdx.x * 256 + threadIdx.x;
    int i = gid * 4;
    const float* src = blockIdx.y == 0 ? fa : fb;
    unsigned short* dst = blockIdx.y == 0 ? Abf : Bbf;
    float4 v = *reinterpret_cast<const float4*>(src + i);
    ushort4 o;
    o.x = f2bf(v.x); o.y = f2bf(v.y); o.z = f2bf(v.z); o.w = f2bf(v.w);
    *reinterpret_cast<ushort4*>(dst + i) = o;

    if (blockIdx.y == 0 && (gid & 31) == 0) {
        int row = gid >> 5;                 // i / CD
        int t = tgt[row];
        int slot = atomicAdd(&cnt[t], 1);
        if (slot < MAXC) bucket[t * MAXC + slot] = (unsigned short)row;
    }
}

// One wave per class: exact f32 class sums h[c]=sum fa rows, g[c]=sum fb rows,
// then extra[c] = -2*T*(h.g)/n_c   (0 if empty class).
__global__ __launch_bounds__(64) void classsum_kernel(
    const float* __restrict__ Tptr,
    const float* __restrict__ fa, const float* __restrict__ fb,
    const int* __restrict__ cnt, const unsigned short* __restrict__ bucket,
    float* __restrict__ extra) {
    const int c = blockIdx.x;
    const int lane = threadIdx.x;
    const int n = cnt[c];
    const int m = n < MAXC ? n : MAXC;
    const float* src = lane < 32 ? fa : fb;
    const int d = (lane & 31) * 4;
    float ax = 0.f, ay = 0.f, az = 0.f, aw = 0.f;
    for (int s = 0; s < m; ++s) {
        int row = bucket[c * MAXC + s];
        float4 v = *reinterpret_cast<const float4*>(src + (size_t)row * CD + d);
        ax += v.x; ay += v.y; az += v.z; aw += v.w;
    }
    float bx_ = __shfl_xor(ax, 32), by_ = __shfl_xor(ay, 32);
    float bz_ = __shfl_xor(az, 32), bw_ = __shfl_xor(aw, 32);
    float p = ax * bx_ + ay * by_ + az * bz_ + aw * bw_;
    #pragma unroll
    for (int off = 1; off < 32; off <<= 1) p += __shfl_xor(p, off);
    if (lane == 0) extra[c] = n > 0 ? (-2.0f * Tptr[0] * p / (float)n) : 0.f;
}

// Block = 128-row strip x 1024-col chunk of S = T*(fa.fb^T).
// A staged once; 16 B-subtiles (64 cols) streamed with LDS double-buffering.
// rE persists in registers across subtiles (one rowPart write per block);
// col partials LDS-reduced per subtile, ONE writer per column per block.
__global__ __launch_bounds__(256) void tile_kernel(
    const float* __restrict__ Tptr,
    const unsigned short* __restrict__ Abf,
    const unsigned short* __restrict__ Bbf,
    float* __restrict__ rowE, float* __restrict__ colE,
    float* __restrict__ rowPart, float* __restrict__ colPart,
    int store_mode)
{
    __shared__ __align__(16) unsigned short sA[128 * 128];
    __shared__ __align__(16) unsigned short sB[2][64 * 128];
    __shared__ float colRed[2][4][64];

    const int tid   = threadIdx.x;
    const int bx    = blockIdx.x;      // col chunk 0..7 (1024 cols)
    const int by    = blockIdx.y;      // row strip 0..63 (128 rows)
    const int brow  = by * 128;
    const int cbase = bx * 1024;
    const float T   = Tptr[0];
    const float Tl2 = T * 1.44269504088896340736f;   // T*log2(e)

    // ---- stage A strip once (swizzled source, linear LDS dest; rule 21) ----
    #pragma unroll
    for (int it = 0; it < 8; ++it) {
        int idx = it * 256 + tid;
        int r = idx >> 4, q = idx & 15;
        const unsigned short* src = Abf + (size_t)(brow + r) * CD + ((q ^ (r & 7)) * 8);
        __builtin_amdgcn_global_load_lds((const __attribute__((address_space(1))) void*)src,
                                         (__attribute__((address_space(3))) void*)&sA[idx * 8],
                                         16, 0, 0);
    }
    // ---- stage first B subtile ----
    #pragma unroll
    for (int it = 0; it < 4; ++it) {
        int idx = it * 256 + tid;
        int r = idx >> 4, q = idx & 15;
        const unsigned short* src = Bbf + (size_t)(cbase + r) * CD + ((q ^ (r & 7)) * 8);
        __builtin_amdgcn_global_load_lds((const __attribute__((address_space(1))) void*)src,
                                         (__attribute__((address_space(3))) void*)&sB[0][idx * 8],
                                         16, 0, 0);
    }
    __syncthreads();

    const int lane = tid & 63;
    const int w    = tid >> 6;          // wave owns rows w*32..w*32+31, all 64 cols
    const int colg = lane & 15;
    const int rowg = lane >> 4;

    float rE[2][4] = {{0.f, 0.f, 0.f, 0.f}, {0.f, 0.f, 0.f, 0.f}};

    for (int ct = 0; ct < 16; ++ct) {
        const int cur = ct & 1;
        // prefetch next B subtile into the other buffer (completes under compute)
        if (ct < 15) {
            int bcolN = cbase + (ct + 1) * 64;
            #pragma unroll
            for (int it = 0; it < 4; ++it) {
                int idx = it * 256 + tid;
                int r = idx >> 4, q = idx & 15;
                const unsigned short* src = Bbf + (size_t)(bcolN + r) * CD + ((q ^ (r & 7)) * 8);
                __builtin_amdgcn_global_load_lds((const __attribute__((address_space(1))) void*)src,
                                                 (__attribute__((address_space(3))) void*)&sB[cur ^ 1][idx * 8],
                                                 16, 0, 0);
            }
        }

        f32x4 acc[2][4];
        #pragma unroll
        for (int m = 0; m < 2; ++m)
            #pragma unroll
            for (int n = 0; n < 4; ++n)
                acc[m][n] = (f32x4){0.f, 0.f, 0.f, 0.f};

        #pragma unroll
        for (int kk = 0; kk < 4; ++kk) {
            bf16x8 af[2], bfr[4];
            #pragma unroll
            for (int m = 0; m < 2; ++m) {
                int r = w * 32 + m * 16 + colg;
                int slot = (kk * 4 + rowg) ^ (r & 7);
                af[m] = *reinterpret_cast<const bf16x8*>(&sA[r * 128 + slot * 8]);
            }
            #pragma unroll
            for (int n = 0; n < 4; ++n) {
                int r = n * 16 + colg;
                int slot = (kk * 4 + rowg) ^ (r & 7);
                bfr[n] = *reinterpret_cast<const bf16x8*>(&sB[cur][r * 128 + slot * 8]);
            }
            #pragma unroll
            for (int m = 0; m < 2; ++m)
                #pragma unroll
                for (int n = 0; n < 4; ++n)
                    acc[m][n] = __builtin_amdgcn_mfma_f32_16x16x32_bf16(af[m], bfr[n], acc[m][n], 0, 0, 0);
        }

        // epilogue: e = exp2(Tl2*(d-1)); D layout: col=lane&15, row=rowg*4+j (m89)
        float cE[4] = {0.f, 0.f, 0.f, 0.f};
        #pragma unroll
        for (int m = 0; m < 2; ++m)
            #pragma unroll
            for (int n = 0; n < 4; ++n)
                #pragma unroll
                for (int j = 0; j < 4; ++j) {
                    float e = exp2f(__builtin_fmaf(acc[m][n][j], Tl2, -Tl2));
                    rE[m][j] += e;
                    cE[n]    += e;
                }

        // per-subtile col partials: fold lane bits 4..5, per-wave -> LDS (dbuf'd)
        #pragma unroll
        for (int n = 0; n < 4; ++n) {
            float e = cE[n];
            e += __shfl_xor(e, 16);
            e += __shfl_xor(e, 32);
            if (rowg == 0) colRed[cur][w][n * 16 + colg] = e;
        }
        __syncthreads();   // colRed visible; next-B stage drained; sB[cur] free
        if (tid < 64) {
            float s = colRed[cur][0][tid] + colRed[cur][1][tid]
                    + colRed[cur][2][tid] + colRed[cur][3][tid];
            int col = cbase + ct * 64 + tid;
            if (store_mode) colPart[(size_t)by * CN + col] = s;
            else            atomicAdd(&colE[col], s);
        }
        // no extra barrier: colRed[cur]'s next write (iter ct+2) is ordered
        // after this read by iter ct+1's barrier; buffers alternate.
    }

    // row sums: fold 16 col-groups (lane bits 0..3); one writer per row slot
    #pragma unroll
    for (int m = 0; m < 2; ++m)
        #pragma unroll
        for (int j = 0; j < 4; ++j) {
            float e = rE[m][j];
            #pragma unroll
            for (int off = 1; off < 16; off <<= 1) e += __shfl_xor(e, off);
            if (colg == 0) {
                int row = brow + w * 32 + m * 16 + rowg * 4 + j;
                if (store_mode) rowPart[(size_t)bx * CN + row] = e;
                else            atomicAdd(&rowE[row], e);
            }
        }
}

// Sum partials, add lse terms and class terms, scale 1/(2N).
__global__ __launch_bounds__(256) void finalize_kernel(
    const float* __restrict__ Tptr,
    const float* __restrict__ rowE, const float* __restrict__ colE,
    const float* __restrict__ rowPart, const float* __restrict__ colPart,
    const float* __restrict__ extra,
    float* __restrict__ out, int store_mode)
{
    __shared__ float red[4];
    const int tid = threadIdx.x;
    int i = blockIdx.x * 256 + tid;              // 0 .. 2*CN+NCLS-1 (padded)
    const float T = Tptr[0];
    float v = 0.f;
    if (i < CN) {
        float se;
        if (store_mode) {
            se = 0.f;
            #pragma unroll
            for (int p = 0; p < 8; ++p) se += rowPart[(size_t)p * CN + i];
        } else se = rowE[i];
        v = T + logf(se);
    } else if (i < 2 * CN) {
        int c = i - CN;
        float se;
        if (store_mode) {
            se = 0.f;
            #pragma unroll 4
            for (int p = 0; p < 64; ++p) se += colPart[(size_t)p * CN + c];
        } else se = colE[c];
        v = T + logf(se);
    } else if (i < 2 * CN + NCLS) {
        v = extra[i - 2 * CN];
    }
    #pragma unroll
    for (int off = 1; off < 64; off <<= 1) v += __shfl_xor(v, off);
    if ((tid & 63) == 0) red[tid >> 6] = v;
    __syncthreads();
    if (tid == 0) {
        float tot = red[0] + red[1] + red[2] + red[3];
        atomicAdd(out, tot * (1.0f / (2.0f * (float)CN)));
    }
}

extern "C" void kernel_launch(void* const* d_in, const int* in_sizes, int n_in,
                              void* d_out, int out_size, void* d_ws, size_t ws_size,
                              hipStream_t stream) {
    const float* T  = (const float*)d_in[0];
    const float* fa = (const float*)d_in[1];
    const float* fb = (const float*)d_in[2];
    const int* tgt  = (const int*)d_in[3];
    float* out      = (float*)d_out;

    char* ws = (char*)d_ws;
    unsigned short* Abf = (unsigned short*)ws;
    unsigned short* Bbf = (unsigned short*)(ws + WS_B_OFF);
    int*   cnt    = (int*)(ws + WS_CNT_OFF);
    float* extra  = (float*)(ws + WS_EXTRA_OFF);
    float* rowE   = (float*)(ws + WS_ROWE_OFF);
    float* colE   = (float*)(ws + WS_COLE_OFF);
    unsigned short* bucket = (unsigned short*)(ws + WS_BKT_OFF);
    float* rowPart = (float*)(ws + WS_ROWP_OFF);
    float* colPart = (float*)(ws + WS_COLP_OFF);

    const int store_mode = (ws_size >= WS_FAST_BYTES) ? 1 : 0;

    hipMemsetAsync(out, 0, sizeof(float), stream);
    hipMemsetAsync(ws + WS_CNT_OFF, 0, WS_ZERO_BYTES, stream);

    convert_kernel<<<dim3(CN * CD / (256 * 4), 2), 256, 0, stream>>>(fa, fb, Abf, Bbf, tgt, cnt, bucket);
    classsum_kernel<<<NCLS, 64, 0, stream>>>(T, fa, fb, cnt, bucket, extra);

    dim3 grid(8, 64);   // col chunks x row strips; 512 blocks = 2/CU, co-resident
    tile_kernel<<<grid, 256, 0, stream>>>(T, Abf, Bbf, rowE, colE, rowPart, colPart, store_mode);

    finalize_kernel<<<(2 * CN + NCLS + 255) / 256, 256, 0, stream>>>(
        T, rowE, colE, rowPart, colPart, extra, out, store_mode);
}

// Round 11
// 126.055 us; speedup vs baseline: 1.7426x; 1.0421x over previous
//
#include <hip/hip_runtime.h>
#include <hip/hip_bf16.h>

// N=8192, D=128, NUM_CLASSES=1000
#define CN 8192
#define CD 128
#define NCLS 1000
#define MAXC 256
#define CLS_BLOCKS 250     // 4 classes/block (4 waves) * 250 = 1000
#define TILE_BLOCKS 512    // 8 col-chunks x 64 row-strips

typedef __attribute__((ext_vector_type(8))) short bf16x8;
typedef __attribute__((ext_vector_type(4))) float f32x4;

// ---- ws layout (bytes) ----
// 0x000000 Abf 2MB | 0x200000 Bbf 2MB
// 0x400000 cnt 4KB | 0x401000 extra 4KB
// 0x402000 rowE 32KB | 0x40A000 colE 32KB      (fallback atomic mode)
// 0x412000 acc(f32), done(u32)
// 0x413000 bucket ushort 1000*256*2 = 500KB
// 0x490000 rowPart 8*8192*4 = 256KB            (store mode)
// 0x890000 colPart 64*8192*4 = 2MB -> end 0xA90000
#define WS_B_OFF     0x200000u
#define WS_CNT_OFF   0x400000u
#define WS_EXTRA_OFF 0x401000u
#define WS_ROWE_OFF  0x402000u
#define WS_COLE_OFF  0x40A000u
#define WS_ACC_OFF   0x412000u
#define WS_DONE_OFF  0x412004u
#define WS_BKT_OFF   0x413000u
#define WS_ROWP_OFF  0x490000u
#define WS_COLP_OFF  0x890000u
#define WS_FAST_BYTES 0xA90000u
#define WS_ZERO_BYTES 0x12100u   // cnt + extra + rowE + colE + acc/done

__device__ inline unsigned short f2bf(float f) {
    unsigned int u = __float_as_uint(f);
    return (unsigned short)((u + 0x7FFFu + ((u >> 16) & 1u)) >> 16);   // RNE
}

// f32 -> bf16 for both matrices; fused per-row class-bucket build (blockIdx.y==0).
__global__ void convert_kernel(const float* __restrict__ fa, const float* __restrict__ fb,
                               unsigned short* __restrict__ Abf, unsigned short* __restrict__ Bbf,
                               const int* __restrict__ tgt,
                               int* __restrict__ cnt, unsigned short* __restrict__ bucket) {
    int gid = blockIdx.x * 256 + threadIdx.x;
    int i = gid * 4;
    const float* src = blockIdx.y == 0 ? fa : fb;
    unsigned short* dst = blockIdx.y == 0 ? Abf : Bbf;
    float4 v = *reinterpret_cast<const float4*>(src + i);
    ushort4 o;
    o.x = f2bf(v.x); o.y = f2bf(v.y); o.z = f2bf(v.z); o.w = f2bf(v.w);
    *reinterpret_cast<ushort4*>(dst + i) = o;

    if (blockIdx.y == 0 && (gid & 31) == 0) {
        int row = gid >> 5;                 // i / CD
        int t = tgt[row];
        int slot = atomicAdd(&cnt[t], 1);
        if (slot < MAXC) bucket[t * MAXC + slot] = (unsigned short)row;
    }
}

// One dispatch, two roles by blockIdx:
//  bid < CLS_BLOCKS : class-sum blocks (4 waves = 4 classes each)
//  else             : tile blocks (128-row strip x 1024-col chunk), round-10 body
__global__ __launch_bounds__(256) void mega_kernel(
    const float* __restrict__ Tptr,
    const unsigned short* __restrict__ Abf,
    const unsigned short* __restrict__ Bbf,
    const float* __restrict__ fa, const float* __restrict__ fb,
    const int* __restrict__ cnt, const unsigned short* __restrict__ bucket,
    float* __restrict__ extra,
    float* __restrict__ rowE, float* __restrict__ colE,
    float* __restrict__ rowPart, float* __restrict__ colPart,
    int store_mode)
{
    __shared__ __align__(16) unsigned short sA[128 * 128];
    __shared__ __align__(16) unsigned short sB[2][64 * 128];
    __shared__ float colRed[2][4][64];

    const int bid  = blockIdx.x;
    const int tid  = threadIdx.x;
    const int lane = tid & 63;
    const int w    = tid >> 6;

    if (bid < CLS_BLOCKS) {
        // ---- class-sum role: exact f32 h[c]=sum fa rows, g[c]=sum fb rows;
        //      extra[c] = -2*T*(h.g)/n_c ----
        const int c = bid * 4 + w;
        const int n = cnt[c];
        const int m = n < MAXC ? n : MAXC;
        const float* src = lane < 32 ? fa : fb;
        const int d = (lane & 31) * 4;
        float ax = 0.f, ay = 0.f, az = 0.f, aw = 0.f;
        for (int s = 0; s < m; ++s) {
            int row = bucket[c * MAXC + s];
            float4 v = *reinterpret_cast<const float4*>(src + (size_t)row * CD + d);
            ax += v.x; ay += v.y; az += v.z; aw += v.w;
        }
        float bx_ = __shfl_xor(ax, 32), by_ = __shfl_xor(ay, 32);
        float bz_ = __shfl_xor(az, 32), bw_ = __shfl_xor(aw, 32);
        float p = ax * bx_ + ay * by_ + az * bz_ + aw * bw_;
        #pragma unroll
        for (int off = 1; off < 32; off <<= 1) p += __shfl_xor(p, off);
        if (lane == 0) extra[c] = n > 0 ? (-2.0f * Tptr[0] * p / (float)n) : 0.f;
        return;
    }

    // ---- tile role (byte-identical structure to round-10 verified kernel) ----
    const int tb    = bid - CLS_BLOCKS;
    const int bx    = tb & 7;          // col chunk 0..7 (1024 cols)
    const int by    = tb >> 3;         // row strip 0..63 (128 rows)
    const int brow  = by * 128;
    const int cbase = bx * 1024;
    const float T   = Tptr[0];
    const float Tl2 = T * 1.44269504088896340736f;   // T*log2(e)

    #pragma unroll
    for (int it = 0; it < 8; ++it) {               // A strip: 2048 x 16B chunks
        int idx = it * 256 + tid;
        int r = idx >> 4, q = idx & 15;
        const unsigned short* src = Abf + (size_t)(brow + r) * CD + ((q ^ (r & 7)) * 8);
        __builtin_amdgcn_global_load_lds((const __attribute__((address_space(1))) void*)src,
                                         (__attribute__((address_space(3))) void*)&sA[idx * 8],
                                         16, 0, 0);
    }
    #pragma unroll
    for (int it = 0; it < 4; ++it) {               // first B subtile
        int idx = it * 256 + tid;
        int r = idx >> 4, q = idx & 15;
        const unsigned short* src = Bbf + (size_t)(cbase + r) * CD + ((q ^ (r & 7)) * 8);
        __builtin_amdgcn_global_load_lds((const __attribute__((address_space(1))) void*)src,
                                         (__attribute__((address_space(3))) void*)&sB[0][idx * 8],
                                         16, 0, 0);
    }
    __syncthreads();

    const int colg = lane & 15;
    const int rowg = lane >> 4;

    float rE[2][4] = {{0.f, 0.f, 0.f, 0.f}, {0.f, 0.f, 0.f, 0.f}};

    for (int ct = 0; ct < 16; ++ct) {
        const int cur = ct & 1;
        if (ct < 15) {
            int bcolN = cbase + (ct + 1) * 64;
            #pragma unroll
            for (int it = 0; it < 4; ++it) {
                int idx = it * 256 + tid;
                int r = idx >> 4, q = idx & 15;
                const unsigned short* src = Bbf + (size_t)(bcolN + r) * CD + ((q ^ (r & 7)) * 8);
                __builtin_amdgcn_global_load_lds((const __attribute__((address_space(1))) void*)src,
                                                 (__attribute__((address_space(3))) void*)&sB[cur ^ 1][idx * 8],
                                                 16, 0, 0);
            }
        }

        f32x4 acc[2][4];
        #pragma unroll
        for (int m = 0; m < 2; ++m)
            #pragma unroll
            for (int n = 0; n < 4; ++n)
                acc[m][n] = (f32x4){0.f, 0.f, 0.f, 0.f};

        #pragma unroll
        for (int kk = 0; kk < 4; ++kk) {
            bf16x8 af[2], bfr[4];
            #pragma unroll
            for (int m = 0; m < 2; ++m) {
                int r = w * 32 + m * 16 + colg;
                int slot = (kk * 4 + rowg) ^ (r & 7);
                af[m] = *reinterpret_cast<const bf16x8*>(&sA[r * 128 + slot * 8]);
            }
            #pragma unroll
            for (int n = 0; n < 4; ++n) {
                int r = n * 16 + colg;
                int slot = (kk * 4 + rowg) ^ (r & 7);
                bfr[n] = *reinterpret_cast<const bf16x8*>(&sB[cur][r * 128 + slot * 8]);
            }
            #pragma unroll
            for (int m = 0; m < 2; ++m)
                #pragma unroll
                for (int n = 0; n < 4; ++n)
                    acc[m][n] = __builtin_amdgcn_mfma_f32_16x16x32_bf16(af[m], bfr[n], acc[m][n], 0, 0, 0);
        }

        float cE[4] = {0.f, 0.f, 0.f, 0.f};
        #pragma unroll
        for (int m = 0; m < 2; ++m)
            #pragma unroll
            for (int n = 0; n < 4; ++n)
                #pragma unroll
                for (int j = 0; j < 4; ++j) {
                    float e = exp2f(__builtin_fmaf(acc[m][n][j], Tl2, -Tl2));
                    rE[m][j] += e;
                    cE[n]    += e;
                }

        #pragma unroll
        for (int n = 0; n < 4; ++n) {
            float e = cE[n];
            e += __shfl_xor(e, 16);
            e += __shfl_xor(e, 32);
            if (rowg == 0) colRed[cur][w][n * 16 + colg] = e;
        }
        __syncthreads();   // colRed visible; next-B stage drained; sB[cur] free
        if (tid < 64) {
            float s = colRed[cur][0][tid] + colRed[cur][1][tid]
                    + colRed[cur][2][tid] + colRed[cur][3][tid];
            int col = cbase + ct * 64 + tid;
            if (store_mode) colPart[(size_t)by * CN + col] = s;
            else            atomicAdd(&colE[col], s);
        }
        // colRed[cur]'s next write (iter ct+2) is ordered after this read by
        // iter ct+1's barrier; buffers alternate.
    }

    #pragma unroll
    for (int m = 0; m < 2; ++m)
        #pragma unroll
        for (int j = 0; j < 4; ++j) {
            float e = rE[m][j];
            #pragma unroll
            for (int off = 1; off < 16; off <<= 1) e += __shfl_xor(e, off);
            if (colg == 0) {
                int row = brow + w * 32 + m * 16 + rowg * 4 + j;
                if (store_mode) rowPart[(size_t)bx * CN + row] = e;
                else            atomicAdd(&rowE[row], e);
            }
        }
}

// Sum partials + lse + class terms; last-done block writes out[0] (no out memset).
__global__ __launch_bounds__(256) void finalize_kernel(
    const float* __restrict__ Tptr,
    const float* __restrict__ rowE, const float* __restrict__ colE,
    const float* __restrict__ rowPart, const float* __restrict__ colPart,
    const float* __restrict__ extra,
    float* __restrict__ wsAcc, unsigned int* __restrict__ wsDone,
    float* __restrict__ out, int store_mode)
{
    __shared__ float red[4];
    const int tid = threadIdx.x;
    int i = blockIdx.x * 256 + tid;              // 0 .. 2*CN+NCLS-1 (padded)
    const float T = Tptr[0];
    float v = 0.f;
    if (i < CN) {
        float se;
        if (store_mode) {
            se = 0.f;
            #pragma unroll
            for (int p = 0; p < 8; ++p) se += rowPart[(size_t)p * CN + i];
        } else se = rowE[i];
        v = T + logf(se);
    } else if (i < 2 * CN) {
        int c = i - CN;
        float se;
        if (store_mode) {
            se = 0.f;
            #pragma unroll 4
            for (int p = 0; p < 64; ++p) se += colPart[(size_t)p * CN + c];
        } else se = colE[c];
        v = T + logf(se);
    } else if (i < 2 * CN + NCLS) {
        v = extra[i - 2 * CN];
    }
    #pragma unroll
    for (int off = 1; off < 64; off <<= 1) v += __shfl_xor(v, off);
    if ((tid & 63) == 0) red[tid >> 6] = v;
    __syncthreads();
    if (tid == 0) {
        float tot = red[0] + red[1] + red[2] + red[3];
        atomicAdd(wsAcc, tot);
        __threadfence();
        unsigned int old = atomicAdd(wsDone, 1u);
        if (old == gridDim.x - 1) {
            float total = atomicAdd(wsAcc, 0.0f);   // read full sum (returns old)
            out[0] = total * (1.0f / (2.0f * (float)CN));
        }
    }
}

extern "C" void kernel_launch(void* const* d_in, const int* in_sizes, int n_in,
                              void* d_out, int out_size, void* d_ws, size_t ws_size,
                              hipStream_t stream) {
    const float* T  = (const float*)d_in[0];
    const float* fa = (const float*)d_in[1];
    const float* fb = (const float*)d_in[2];
    const int* tgt  = (const int*)d_in[3];
    float* out      = (float*)d_out;

    char* ws = (char*)d_ws;
    unsigned short* Abf = (unsigned short*)ws;
    unsigned short* Bbf = (unsigned short*)(ws + WS_B_OFF);
    int*   cnt    = (int*)(ws + WS_CNT_OFF);
    float* extra  = (float*)(ws + WS_EXTRA_OFF);
    float* rowE   = (float*)(ws + WS_ROWE_OFF);
    float* colE   = (float*)(ws + WS_COLE_OFF);
    float* wsAcc  = (float*)(ws + WS_ACC_OFF);
    unsigned int* wsDone = (unsigned int*)(ws + WS_DONE_OFF);
    unsigned short* bucket = (unsigned short*)(ws + WS_BKT_OFF);
    float* rowPart = (float*)(ws + WS_ROWP_OFF);
    float* colPart = (float*)(ws + WS_COLP_OFF);

    const int store_mode = (ws_size >= WS_FAST_BYTES) ? 1 : 0;

    hipMemsetAsync(ws + WS_CNT_OFF, 0, WS_ZERO_BYTES, stream);

    convert_kernel<<<dim3(CN * CD / (256 * 4), 2), 256, 0, stream>>>(fa, fb, Abf, Bbf, tgt, cnt, bucket);

    mega_kernel<<<CLS_BLOCKS + TILE_BLOCKS, 256, 0, stream>>>(
        T, Abf, Bbf, fa, fb, cnt, bucket, extra,
        rowE, colE, rowPart, colPart, store_mode);

    finalize_kernel<<<(2 * CN + NCLS + 255) / 256, 256, 0, stream>>>(
        T, rowE, colE, rowPart, colPart, extra, wsAcc, wsDone, out, store_mode);
}

// Round 12
// 119.549 us; speedup vs baseline: 1.8374x; 1.0544x over previous
//
#include <hip/hip_runtime.h>
#include <hip/hip_bf16.h>

// N=8192, D=128, NUM_CLASSES=1000
#define CN 8192
#define CD 128
#define NCLS 1000
#define MAXC 256
#define CLS_BLOCKS 250     // 4 classes/block (4 waves) * 250 = 1000
#define TILE_BLOCKS 1024   // 16 col-chunks(512 cols) x 64 row-strips(128 rows)

typedef __attribute__((ext_vector_type(8))) short bf16x8;
typedef __attribute__((ext_vector_type(4))) float f32x4;
typedef __attribute__((ext_vector_type(2))) float f32x2;

// ---- ws layout (bytes) ----
// 0x000000 Abf 2MB | 0x200000 Bbf 2MB
// 0x400000 cnt 4KB | 0x401000 extra 4KB
// 0x402000 rowE 32KB | 0x40A000 colE 32KB      (fallback atomic mode)
// 0x412000 acc(f32), done(u32)
// 0x413000 bucket ushort 1000*256*2 = 500KB
// 0x490000 rowPart 16*8192*4 = 512KB           (store mode)
// 0x890000 colPart 64*8192*4 = 2MB -> end 0xA90000
#define WS_B_OFF     0x200000u
#define WS_CNT_OFF   0x400000u
#define WS_EXTRA_OFF 0x401000u
#define WS_ROWE_OFF  0x402000u
#define WS_COLE_OFF  0x40A000u
#define WS_ACC_OFF   0x412000u
#define WS_DONE_OFF  0x412004u
#define WS_BKT_OFF   0x413000u
#define WS_ROWP_OFF  0x490000u
#define WS_COLP_OFF  0x890000u
#define WS_FAST_BYTES 0xA90000u
#define WS_ZERO_BYTES 0x12100u   // cnt + extra + rowE + colE + acc/done

__device__ inline unsigned short f2bf(float f) {
    unsigned int u = __float_as_uint(f);
    return (unsigned short)((u + 0x7FFFu + ((u >> 16) & 1u)) >> 16);   // RNE
}

// f32 -> bf16 for both matrices; fused per-row class-bucket build (blockIdx.y==0).
__global__ void convert_kernel(const float* __restrict__ fa, const float* __restrict__ fb,
                               unsigned short* __restrict__ Abf, unsigned short* __restrict__ Bbf,
                               const int* __restrict__ tgt,
                               int* __restrict__ cnt, unsigned short* __restrict__ bucket) {
    int gid = blockIdx.x * 256 + threadIdx.x;
    int i = gid * 4;
    const float* src = blockIdx.y == 0 ? fa : fb;
    unsigned short* dst = blockIdx.y == 0 ? Abf : Bbf;
    float4 v = *reinterpret_cast<const float4*>(src + i);
    ushort4 o;
    o.x = f2bf(v.x); o.y = f2bf(v.y); o.z = f2bf(v.z); o.w = f2bf(v.w);
    *reinterpret_cast<ushort4*>(dst + i) = o;

    if (blockIdx.y == 0 && (gid & 31) == 0) {
        int row = gid >> 5;                 // i / CD
        int t = tgt[row];
        int slot = atomicAdd(&cnt[t], 1);
        if (slot < MAXC) bucket[t * MAXC + slot] = (unsigned short)row;
    }
}

// One dispatch, two roles by blockIdx:
//  bid < CLS_BLOCKS : class-sum blocks (4 waves = 4 classes each)
//  else             : tile blocks (128-row strip x 512-col chunk)
__global__ __launch_bounds__(256, 4) void mega_kernel(
    const float* __restrict__ Tptr,
    const unsigned short* __restrict__ Abf,
    const unsigned short* __restrict__ Bbf,
    const float* __restrict__ fa, const float* __restrict__ fb,
    const int* __restrict__ cnt, const unsigned short* __restrict__ bucket,
    float* __restrict__ extra,
    float* __restrict__ rowE, float* __restrict__ colE,
    float* __restrict__ rowPart, float* __restrict__ colPart,
    int store_mode)
{
    __shared__ __align__(16) unsigned short sB[2][64 * 128];
    __shared__ float colRed[2][4][64];

    const int bid  = blockIdx.x;
    const int tid  = threadIdx.x;
    const int lane = tid & 63;
    const int w    = tid >> 6;

    if (bid < CLS_BLOCKS) {
        // ---- class-sum role: exact f32 h[c]=sum fa rows, g[c]=sum fb rows;
        //      extra[c] = -2*T*(h.g)/n_c ----
        const int c = bid * 4 + w;
        const int n = cnt[c];
        const int m = n < MAXC ? n : MAXC;
        const float* src = lane < 32 ? fa : fb;
        const int d = (lane & 31) * 4;
        float ax = 0.f, ay = 0.f, az = 0.f, aw = 0.f;
        for (int s = 0; s < m; ++s) {
            int row = bucket[c * MAXC + s];
            float4 v = *reinterpret_cast<const float4*>(src + (size_t)row * CD + d);
            ax += v.x; ay += v.y; az += v.z; aw += v.w;
        }
        float bx_ = __shfl_xor(ax, 32), by_ = __shfl_xor(ay, 32);
        float bz_ = __shfl_xor(az, 32), bw_ = __shfl_xor(aw, 32);
        float p = ax * bx_ + ay * by_ + az * bz_ + aw * bw_;
        #pragma unroll
        for (int off = 1; off < 32; off <<= 1) p += __shfl_xor(p, off);
        if (lane == 0) extra[c] = n > 0 ? (-2.0f * Tptr[0] * p / (float)n) : 0.f;
        return;
    }

    // ---- tile role ----
    const int tb    = bid - CLS_BLOCKS;
    const int bx    = tb & 15;         // col chunk 0..15 (512 cols)
    const int by    = tb >> 4;         // row strip 0..63 (128 rows)
    const int brow  = by * 128;
    const int cbase = bx * 512;
    const float T    = Tptr[0];
    const float Tl2  = T * 1.44269504088896340736f;   // T*log2(e)
    const f32x2 Tl2v  = {Tl2, Tl2};
    const f32x2 nTl2v = {-Tl2, -Tl2};

    const int colg = lane & 15;
    const int rowg = lane >> 4;

    // A fragments once per block, direct from global (linear bf16, no swizzle):
    // af[m][kk] = Abf[(brow + w*32 + m*16 + colg)*CD + (kk*4+rowg)*8 .. +8]
    // (equivalent to the verified LDS path: swizzles cancel)
    bf16x8 afr[2][4];
    #pragma unroll
    for (int m = 0; m < 2; ++m) {
        const unsigned short* arow = Abf + (size_t)(brow + w * 32 + m * 16 + colg) * CD + rowg * 8;
        #pragma unroll
        for (int kk = 0; kk < 4; ++kk)
            afr[m][kk] = *reinterpret_cast<const bf16x8*>(arow + kk * 32);
    }

    // first B subtile stage (gload_lds w=16, inverse-swizzled source; rule 21)
    #pragma unroll
    for (int it = 0; it < 4; ++it) {
        int idx = it * 256 + tid;
        int r = idx >> 4, q = idx & 15;
        const unsigned short* src = Bbf + (size_t)(cbase + r) * CD + ((q ^ (r & 7)) * 8);
        __builtin_amdgcn_global_load_lds((const __attribute__((address_space(1))) void*)src,
                                         (__attribute__((address_space(3))) void*)&sB[0][idx * 8],
                                         16, 0, 0);
    }
    __syncthreads();

    f32x2 rE2[2][2] = {{{0.f, 0.f}, {0.f, 0.f}}, {{0.f, 0.f}, {0.f, 0.f}}};

    for (int ct = 0; ct < 8; ++ct) {
        const int cur = ct & 1;
        if (ct < 7) {
            int bcolN = cbase + (ct + 1) * 64;
            #pragma unroll
            for (int it = 0; it < 4; ++it) {
                int idx = it * 256 + tid;
                int r = idx >> 4, q = idx & 15;
                const unsigned short* src = Bbf + (size_t)(bcolN + r) * CD + ((q ^ (r & 7)) * 8);
                __builtin_amdgcn_global_load_lds((const __attribute__((address_space(1))) void*)src,
                                                 (__attribute__((address_space(3))) void*)&sB[cur ^ 1][idx * 8],
                                                 16, 0, 0);
            }
        }

        f32x4 acc[2][4];
        #pragma unroll
        for (int m = 0; m < 2; ++m)
            #pragma unroll
            for (int n = 0; n < 4; ++n)
                acc[m][n] = (f32x4){0.f, 0.f, 0.f, 0.f};

        #pragma unroll
        for (int kk = 0; kk < 4; ++kk) {
            bf16x8 bfr[4];
            #pragma unroll
            for (int n = 0; n < 4; ++n) {
                int r = n * 16 + colg;
                int slot = (kk * 4 + rowg) ^ (r & 7);
                bfr[n] = *reinterpret_cast<const bf16x8*>(&sB[cur][r * 128 + slot * 8]);
            }
            #pragma unroll
            for (int m = 0; m < 2; ++m)
                #pragma unroll
                for (int n = 0; n < 4; ++n)
                    acc[m][n] = __builtin_amdgcn_mfma_f32_16x16x32_bf16(afr[m][kk], bfr[n], acc[m][n], 0, 0, 0);
        }

        // packed epilogue: e = exp2(d*Tl2 - Tl2); D layout col=lane&15, row=rowg*4+j
        f32x2 cE2[4] = {{0.f, 0.f}, {0.f, 0.f}, {0.f, 0.f}, {0.f, 0.f}};
        #pragma unroll
        for (int m = 0; m < 2; ++m)
            #pragma unroll
            for (int n = 0; n < 4; ++n) {
                f32x4 a4 = acc[m][n];
                f32x2 d01 = {a4[0], a4[1]};
                f32x2 d23 = {a4[2], a4[3]};
                f32x2 t01 = __builtin_elementwise_fma(d01, Tl2v, nTl2v);
                f32x2 t23 = __builtin_elementwise_fma(d23, Tl2v, nTl2v);
                f32x2 e01 = {exp2f(t01.x), exp2f(t01.y)};
                f32x2 e23 = {exp2f(t23.x), exp2f(t23.y)};
                rE2[m][0] += e01;
                rE2[m][1] += e23;
                cE2[n] += e01;
                cE2[n] += e23;
            }

        // per-subtile col partials: horizontal fold + lane bits 4..5 -> LDS (dbuf'd)
        #pragma unroll
        for (int n = 0; n < 4; ++n) {
            float e = cE2[n].x + cE2[n].y;
            e += __shfl_xor(e, 16);
            e += __shfl_xor(e, 32);
            if (rowg == 0) colRed[cur][w][n * 16 + colg] = e;
        }
        __syncthreads();   // colRed visible; next-B stage drained; sB[cur] free
        if (tid < 64) {
            float s = colRed[cur][0][tid] + colRed[cur][1][tid]
                    + colRed[cur][2][tid] + colRed[cur][3][tid];
            int col = cbase + ct * 64 + tid;
            if (store_mode) colPart[(size_t)by * CN + col] = s;
            else            atomicAdd(&colE[col], s);
        }
        // colRed[cur]'s next write (iter ct+2) is ordered after this read by
        // iter ct+1's barrier; buffers alternate.
    }

    // row sums: fold 16 col-groups (lane bits 0..3); one writer per row slot
    #pragma unroll
    for (int m = 0; m < 2; ++m)
        #pragma unroll
        for (int jp = 0; jp < 2; ++jp) {
            f32x2 e = rE2[m][jp];
            #pragma unroll
            for (int off = 1; off < 16; off <<= 1) {
                e.x += __shfl_xor(e.x, off);
                e.y += __shfl_xor(e.y, off);
            }
            if (colg == 0) {
                int row0 = brow + w * 32 + m * 16 + rowg * 4 + jp * 2;
                if (store_mode) {
                    rowPart[(size_t)bx * CN + row0]     = e.x;
                    rowPart[(size_t)bx * CN + row0 + 1] = e.y;
                } else {
                    atomicAdd(&rowE[row0],     e.x);
                    atomicAdd(&rowE[row0 + 1], e.y);
                }
            }
        }
}

// Sum partials + lse + class terms; last-done block writes out[0] (no out memset).
__global__ __launch_bounds__(256) void finalize_kernel(
    const float* __restrict__ Tptr,
    const float* __restrict__ rowE, const float* __restrict__ colE,
    const float* __restrict__ rowPart, const float* __restrict__ colPart,
    const float* __restrict__ extra,
    float* __restrict__ wsAcc, unsigned int* __restrict__ wsDone,
    float* __restrict__ out, int store_mode)
{
    __shared__ float red[4];
    const int tid = threadIdx.x;
    int i = blockIdx.x * 256 + tid;              // 0 .. 2*CN+NCLS-1 (padded)
    const float T = Tptr[0];
    float v = 0.f;
    if (i < CN) {
        float se;
        if (store_mode) {
            se = 0.f;
            #pragma unroll
            for (int p = 0; p < 16; ++p) se += rowPart[(size_t)p * CN + i];
        } else se = rowE[i];
        v = T + logf(se);
    } else if (i < 2 * CN) {
        int c = i - CN;
        float se;
        if (store_mode) {
            se = 0.f;
            #pragma unroll 4
            for (int p = 0; p < 64; ++p) se += colPart[(size_t)p * CN + c];
        } else se = colE[c];
        v = T + logf(se);
    } else if (i < 2 * CN + NCLS) {
        v = extra[i - 2 * CN];
    }
    #pragma unroll
    for (int off = 1; off < 64; off <<= 1) v += __shfl_xor(v, off);
    if ((tid & 63) == 0) red[tid >> 6] = v;
    __syncthreads();
    if (tid == 0) {
        float tot = red[0] + red[1] + red[2] + red[3];
        atomicAdd(wsAcc, tot);
        __threadfence();
        unsigned int old = atomicAdd(wsDone, 1u);
        if (old == gridDim.x - 1) {
            float total = atomicAdd(wsAcc, 0.0f);   // read full sum (returns old)
            out[0] = total * (1.0f / (2.0f * (float)CN));
        }
    }
}

extern "C" void kernel_launch(void* const* d_in, const int* in_sizes, int n_in,
                              void* d_out, int out_size, void* d_ws, size_t ws_size,
                              hipStream_t stream) {
    const float* T  = (const float*)d_in[0];
    const float* fa = (const float*)d_in[1];
    const float* fb = (const float*)d_in[2];
    const int* tgt  = (const int*)d_in[3];
    float* out      = (float*)d_out;

    char* ws = (char*)d_ws;
    unsigned short* Abf = (unsigned short*)ws;
    unsigned short* Bbf = (unsigned short*)(ws + WS_B_OFF);
    int*   cnt    = (int*)(ws + WS_CNT_OFF);
    float* extra  = (float*)(ws + WS_EXTRA_OFF);
    float* rowE   = (float*)(ws + WS_ROWE_OFF);
    float* colE   = (float*)(ws + WS_COLE_OFF);
    float* wsAcc  = (float*)(ws + WS_ACC_OFF);
    unsigned int* wsDone = (unsigned int*)(ws + WS_DONE_OFF);
    unsigned short* bucket = (unsigned short*)(ws + WS_BKT_OFF);
    float* rowPart = (float*)(ws + WS_ROWP_OFF);
    float* colPart = (float*)(ws + WS_COLP_OFF);

    const int store_mode = (ws_size >= WS_FAST_BYTES) ? 1 : 0;

    hipMemsetAsync(ws + WS_CNT_OFF, 0, WS_ZERO_BYTES, stream);

    convert_kernel<<<dim3(CN * CD / (256 * 4), 2), 256, 0, stream>>>(fa, fb, Abf, Bbf, tgt, cnt, bucket);

    mega_kernel<<<CLS_BLOCKS + TILE_BLOCKS, 256, 0, stream>>>(
        T, Abf, Bbf, fa, fb, cnt, bucket, extra,
        rowE, colE, rowPart, colPart, store_mode);

    finalize_kernel<<<(2 * CN + NCLS + 255) / 256, 256, 0, stream>>>(
        T, rowE, colE, rowPart, colPart, extra, wsAcc, wsDone, out, store_mode);
}

// Round 13
// 117.547 us; speedup vs baseline: 1.8687x; 1.0170x over previous
//
#include <hip/hip_runtime.h>
#include <hip/hip_bf16.h>

// N=8192, D=128, NUM_CLASSES=1000
#define CN 8192
#define CD 128
#define NCLS 1000
#define MAXC 256
#define CLS_BLOCKS 250     // 4 classes/block (4 waves) * 250 = 1000
#define TILE_BLOCKS 1024   // 16 col-chunks(512 cols) x 64 row-strips(128 rows)

typedef __attribute__((ext_vector_type(8))) short bf16x8;
typedef __attribute__((ext_vector_type(4))) float f32x4;
typedef __attribute__((ext_vector_type(2))) float f32x2;

// ---- ws layout (bytes) ----
// 0x000000 Abf 2MB | 0x200000 Bbf 2MB
// 0x400000 cnt 4KB | 0x401000 extra 4KB
// 0x402000 rowE 32KB | 0x40A000 colE 32KB      (fallback atomic mode)
// 0x412000 acc(f32), done(u32)
// 0x413000 bucket ushort 1000*256*2 = 500KB
// 0x490000 rowPart 16*8192*4 = 512KB           (store mode)
// 0x890000 colPart 64*8192*4 = 2MB -> end 0xA90000
#define WS_B_OFF     0x200000u
#define WS_CNT_OFF   0x400000u
#define WS_EXTRA_OFF 0x401000u
#define WS_ROWE_OFF  0x402000u
#define WS_COLE_OFF  0x40A000u
#define WS_ACC_OFF   0x412000u
#define WS_DONE_OFF  0x412004u
#define WS_BKT_OFF   0x413000u
#define WS_ROWP_OFF  0x490000u
#define WS_COLP_OFF  0x890000u
#define WS_FAST_BYTES 0xA90000u
#define WS_ZERO_BYTES 0x12100u   // cnt + extra + rowE + colE + acc/done

__device__ inline unsigned short f2bf(float f) {
    unsigned int u = __float_as_uint(f);
    return (unsigned short)((u + 0x7FFFu + ((u >> 16) & 1u)) >> 16);   // RNE
}

// f32 -> bf16 for both matrices; fused per-row class-bucket build (blockIdx.y==0).
__global__ void convert_kernel(const float* __restrict__ fa, const float* __restrict__ fb,
                               unsigned short* __restrict__ Abf, unsigned short* __restrict__ Bbf,
                               const int* __restrict__ tgt,
                               int* __restrict__ cnt, unsigned short* __restrict__ bucket) {
    int gid = blockIdx.x * 256 + threadIdx.x;
    int i = gid * 4;
    const float* src = blockIdx.y == 0 ? fa : fb;
    unsigned short* dst = blockIdx.y == 0 ? Abf : Bbf;
    float4 v = *reinterpret_cast<const float4*>(src + i);
    ushort4 o;
    o.x = f2bf(v.x); o.y = f2bf(v.y); o.z = f2bf(v.z); o.w = f2bf(v.w);
    *reinterpret_cast<ushort4*>(dst + i) = o;

    if (blockIdx.y == 0 && (gid & 31) == 0) {
        int row = gid >> 5;                 // i / CD
        int t = tgt[row];
        int slot = atomicAdd(&cnt[t], 1);
        if (slot < MAXC) bucket[t * MAXC + slot] = (unsigned short)row;
    }
}

// One dispatch, two roles by blockIdx:
//  bid < CLS_BLOCKS : class-sum blocks (4 waves = 4 classes each)
//  else             : tile blocks (128-row strip x 512-col chunk)
__global__ __launch_bounds__(256, 4) void mega_kernel(
    const float* __restrict__ Tptr,
    const unsigned short* __restrict__ Abf,
    const unsigned short* __restrict__ Bbf,
    const float* __restrict__ fa, const float* __restrict__ fb,
    const int* __restrict__ cnt, const unsigned short* __restrict__ bucket,
    float* __restrict__ extra,
    float* __restrict__ rowE, float* __restrict__ colE,
    float* __restrict__ rowPart, float* __restrict__ colPart,
    int store_mode)
{
    __shared__ __align__(16) unsigned short sB[2][64 * 128];  // 32 KB
    __shared__ float colRed[8][4][64];                        //  8 KB, one slot/subtile

    const int bid  = blockIdx.x;
    const int tid  = threadIdx.x;
    const int lane = tid & 63;
    const int w    = tid >> 6;

    if (bid < CLS_BLOCKS) {
        // ---- class-sum role: exact f32 h[c]=sum fa rows, g[c]=sum fb rows;
        //      extra[c] = -2*T*(h.g)/n_c ----
        const int c = bid * 4 + w;
        const int n = cnt[c];
        const int m = n < MAXC ? n : MAXC;
        const float* src = lane < 32 ? fa : fb;
        const int d = (lane & 31) * 4;
        float ax = 0.f, ay = 0.f, az = 0.f, aw = 0.f;
        for (int s = 0; s < m; ++s) {
            int row = bucket[c * MAXC + s];
            float4 v = *reinterpret_cast<const float4*>(src + (size_t)row * CD + d);
            ax += v.x; ay += v.y; az += v.z; aw += v.w;
        }
        float bx_ = __shfl_xor(ax, 32), by_ = __shfl_xor(ay, 32);
        float bz_ = __shfl_xor(az, 32), bw_ = __shfl_xor(aw, 32);
        float p = ax * bx_ + ay * by_ + az * bz_ + aw * bw_;
        #pragma unroll
        for (int off = 1; off < 32; off <<= 1) p += __shfl_xor(p, off);
        if (lane == 0) extra[c] = n > 0 ? (-2.0f * Tptr[0] * p / (float)n) : 0.f;
        return;
    }

    // ---- tile role ----
    const int tb    = bid - CLS_BLOCKS;
    const int bx    = tb & 15;         // col chunk 0..15 (512 cols)
    const int by    = tb >> 4;         // row strip 0..63 (128 rows)
    const int brow  = by * 128;
    const int cbase = bx * 512;
    const float T    = Tptr[0];
    const float Tl2  = T * 1.44269504088896340736f;   // T*log2(e)
    const f32x2 Tl2v  = {Tl2, Tl2};
    const f32x2 nTl2v = {-Tl2, -Tl2};

    const int colg = lane & 15;
    const int rowg = lane >> 4;

    // A fragments once per block, direct from global (linear bf16; swizzles cancel):
    bf16x8 afr[2][4];
    #pragma unroll
    for (int m = 0; m < 2; ++m) {
        const unsigned short* arow = Abf + (size_t)(brow + w * 32 + m * 16 + colg) * CD + rowg * 8;
        #pragma unroll
        for (int kk = 0; kk < 4; ++kk)
            afr[m][kk] = *reinterpret_cast<const bf16x8*>(arow + kk * 32);
    }
    // Complete afr BEFORE staging so the only in-loop VMEM ops are gload_lds
    // (no register consumers -> no compiler-auto vmcnt in the loop).
    asm volatile("s_waitcnt vmcnt(0)" ::: "memory");
    __builtin_amdgcn_sched_barrier(0);

    // stage subtile ct into sB[buf] (gload_lds w=16, inverse-swizzled source; rule 21)
    auto stage = [&](int buf, int ctv) {
        int bcol = cbase + ctv * 64;
        #pragma unroll
        for (int it = 0; it < 4; ++it) {
            int idx = it * 256 + tid;
            int r = idx >> 4, q = idx & 15;
            const unsigned short* src = Bbf + (size_t)(bcol + r) * CD + ((q ^ (r & 7)) * 8);
            __builtin_amdgcn_global_load_lds((const __attribute__((address_space(1))) void*)src,
                                             (__attribute__((address_space(3))) void*)&sB[buf][idx * 8],
                                             16, 0, 0);
        }
    };
    stage(0, 0);
    stage(1, 1);

    f32x2 rE2[2][2] = {{{0.f, 0.f}, {0.f, 0.f}}, {{0.f, 0.f}, {0.f, 0.f}}};

    for (int ct = 0; ct < 8; ++ct) {
        const int cur = ct & 1;
        // T4 counted wait: buf[cur] (oldest 4 loads) ready; buf[ct+1]'s 4 stay in flight.
        if (ct < 7) asm volatile("s_waitcnt vmcnt(4)" ::: "memory");
        else        asm volatile("s_waitcnt vmcnt(0)" ::: "memory");
        __builtin_amdgcn_s_barrier();
        __builtin_amdgcn_sched_barrier(0);

        f32x4 acc[2][4];
        #pragma unroll
        for (int m = 0; m < 2; ++m)
            #pragma unroll
            for (int n = 0; n < 4; ++n)
                acc[m][n] = (f32x4){0.f, 0.f, 0.f, 0.f};

        #pragma unroll
        for (int kk = 0; kk < 4; ++kk) {
            bf16x8 bfr[4];
            #pragma unroll
            for (int n = 0; n < 4; ++n) {
                int r = n * 16 + colg;
                int slot = (kk * 4 + rowg) ^ (r & 7);
                bfr[n] = *reinterpret_cast<const bf16x8*>(&sB[cur][r * 128 + slot * 8]);
            }
            #pragma unroll
            for (int m = 0; m < 2; ++m)
                #pragma unroll
                for (int n = 0; n < 4; ++n)
                    acc[m][n] = __builtin_amdgcn_mfma_f32_16x16x32_bf16(afr[m][kk], bfr[n], acc[m][n], 0, 0, 0);
        }

        // packed epilogue: e = exp2(d*Tl2 - Tl2); D layout col=lane&15, row=rowg*4+j
        f32x2 cE2[4] = {{0.f, 0.f}, {0.f, 0.f}, {0.f, 0.f}, {0.f, 0.f}};
        #pragma unroll
        for (int m = 0; m < 2; ++m)
            #pragma unroll
            for (int n = 0; n < 4; ++n) {
                f32x4 a4 = acc[m][n];
                f32x2 d01 = {a4[0], a4[1]};
                f32x2 d23 = {a4[2], a4[3]};
                f32x2 t01 = __builtin_elementwise_fma(d01, Tl2v, nTl2v);
                f32x2 t23 = __builtin_elementwise_fma(d23, Tl2v, nTl2v);
                f32x2 e01 = {exp2f(t01.x), exp2f(t01.y)};
                f32x2 e23 = {exp2f(t23.x), exp2f(t23.y)};
                rE2[m][0] += e01;
                rE2[m][1] += e23;
                cE2[n] += e01;
                cE2[n] += e23;
            }

        // per-subtile col partials -> dedicated colRed slot (read only after loop)
        #pragma unroll
        for (int n = 0; n < 4; ++n) {
            float e = cE2[n].x + cE2[n].y;
            e += __shfl_xor(e, 16);
            e += __shfl_xor(e, 32);
            if (rowg == 0) colRed[ct][w][n * 16 + colg] = e;
        }

        // all waves done reading sB[cur] -> safe to re-stage it for ct+2
        __builtin_amdgcn_s_barrier();
        __builtin_amdgcn_sched_barrier(0);
        if (ct < 6) stage(cur, ct + 2);
    }

    __syncthreads();   // colRed fully visible (drains lgkm, full barrier)

    // col sweep: 512 (subtile,col) entries, one writer each
    #pragma unroll
    for (int q2 = 0; q2 < 2; ++q2) {
        int idx = q2 * 256 + tid;
        int ctq = idx >> 6, col = idx & 63;
        float s = colRed[ctq][0][col] + colRed[ctq][1][col]
                + colRed[ctq][2][col] + colRed[ctq][3][col];
        int gcol = cbase + ctq * 64 + col;
        if (store_mode) colPart[(size_t)by * CN + gcol] = s;
        else            atomicAdd(&colE[gcol], s);
    }

    // row sums: fold 16 col-groups (lane bits 0..3); one writer per row slot
    #pragma unroll
    for (int m = 0; m < 2; ++m)
        #pragma unroll
        for (int jp = 0; jp < 2; ++jp) {
            f32x2 e = rE2[m][jp];
            #pragma unroll
            for (int off = 1; off < 16; off <<= 1) {
                e.x += __shfl_xor(e.x, off);
                e.y += __shfl_xor(e.y, off);
            }
            if (colg == 0) {
                int row0 = brow + w * 32 + m * 16 + rowg * 4 + jp * 2;
                if (store_mode) {
                    rowPart[(size_t)bx * CN + row0]     = e.x;
                    rowPart[(size_t)bx * CN + row0 + 1] = e.y;
                } else {
                    atomicAdd(&rowE[row0],     e.x);
                    atomicAdd(&rowE[row0 + 1], e.y);
                }
            }
        }
}

// Sum partials + lse + class terms; last-done block writes out[0] (no out memset).
__global__ __launch_bounds__(256) void finalize_kernel(
    const float* __restrict__ Tptr,
    const float* __restrict__ rowE, const float* __restrict__ colE,
    const float* __restrict__ rowPart, const float* __restrict__ colPart,
    const float* __restrict__ extra,
    float* __restrict__ wsAcc, unsigned int* __restrict__ wsDone,
    float* __restrict__ out, int store_mode)
{
    __shared__ float red[4];
    const int tid = threadIdx.x;
    int i = blockIdx.x * 256 + tid;              // 0 .. 2*CN+NCLS-1 (padded)
    const float T = Tptr[0];
    float v = 0.f;
    if (i < CN) {
        float se;
        if (store_mode) {
            se = 0.f;
            #pragma unroll
            for (int p = 0; p < 16; ++p) se += rowPart[(size_t)p * CN + i];
        } else se = rowE[i];
        v = T + logf(se);
    } else if (i < 2 * CN) {
        int c = i - CN;
        float se;
        if (store_mode) {
            se = 0.f;
            #pragma unroll 4
            for (int p = 0; p < 64; ++p) se += colPart[(size_t)p * CN + c];
        } else se = colE[c];
        v = T + logf(se);
    } else if (i < 2 * CN + NCLS) {
        v = extra[i - 2 * CN];
    }
    #pragma unroll
    for (int off = 1; off < 64; off <<= 1) v += __shfl_xor(v, off);
    if ((tid & 63) == 0) red[tid >> 6] = v;
    __syncthreads();
    if (tid == 0) {
        float tot = red[0] + red[1] + red[2] + red[3];
        atomicAdd(wsAcc, tot);
        __threadfence();
        unsigned int old = atomicAdd(wsDone, 1u);
        if (old == gridDim.x - 1) {
            float total = atomicAdd(wsAcc, 0.0f);   // read full sum (returns old)
            out[0] = total * (1.0f / (2.0f * (float)CN));
        }
    }
}

extern "C" void kernel_launch(void* const* d_in, const int* in_sizes, int n_in,
                              void* d_out, int out_size, void* d_ws, size_t ws_size,
                              hipStream_t stream) {
    const float* T  = (const float*)d_in[0];
    const float* fa = (const float*)d_in[1];
    const float* fb = (const float*)d_in[2];
    const int* tgt  = (const int*)d_in[3];
    float* out      = (float*)d_out;

    char* ws = (char*)d_ws;
    unsigned short* Abf = (unsigned short*)ws;
    unsigned short* Bbf = (unsigned short*)(ws + WS_B_OFF);
    int*   cnt    = (int*)(ws + WS_CNT_OFF);
    float* extra  = (float*)(ws + WS_EXTRA_OFF);
    float* rowE   = (float*)(ws + WS_ROWE_OFF);
    float* colE   = (float*)(ws + WS_COLE_OFF);
    float* wsAcc  = (float*)(ws + WS_ACC_OFF);
    unsigned int* wsDone = (unsigned int*)(ws + WS_DONE_OFF);
    unsigned short* bucket = (unsigned short*)(ws + WS_BKT_OFF);
    float* rowPart = (float*)(ws + WS_ROWP_OFF);
    float* colPart = (float*)(ws + WS_COLP_OFF);

    const int store_mode = (ws_size >= WS_FAST_BYTES) ? 1 : 0;

    hipMemsetAsync(ws + WS_CNT_OFF, 0, WS_ZERO_BYTES, stream);

    convert_kernel<<<dim3(CN * CD / (256 * 4), 2), 256, 0, stream>>>(fa, fb, Abf, Bbf, tgt, cnt, bucket);

    mega_kernel<<<CLS_BLOCKS + TILE_BLOCKS, 256, 0, stream>>>(
        T, Abf, Bbf, fa, fb, cnt, bucket, extra,
        rowE, colE, rowPart, colPart, store_mode);

    finalize_kernel<<<(2 * CN + NCLS + 255) / 256, 256, 0, stream>>>(
        T, rowE, colE, rowPart, colPart, extra, wsAcc, wsDone, out, store_mode);
}